// Round 14
// baseline (242.329 us; speedup 1.0000x reference)
//
#include <hip/hip_runtime.h>

typedef unsigned int u32;
typedef unsigned char u8;
typedef unsigned long long u64;
typedef int i32x4 __attribute__((ext_vector_type(4)));
typedef int i32x8 __attribute__((ext_vector_type(8)));
typedef float f32x16 __attribute__((ext_vector_type(16)));

// Workspace layout (3.8 MB used):
//   [0, 294912)          Wm fp4: [stp=tap*4+k64][oc][32B] (64 ic nibbles/oc),
//                        8KB per step; nibble 0x2=+1, 0xA=-1 (e2m1), low
//                        nibble = even ic.
//   [589824, +3211264)   bp bitplanes: bp[(n*256+ch)*49 + (px>>6)], bit px&63
#define WM_OFF 0
#define BP_OFF 589824
#define ROWB 14848  // LDS bytes per padded row: 58 w' * 256B (128B data,
                    // scattered over 256B by the 4-bit XOR key -> 2-way reads)

// ---------------------------------------------------------------------------
// Kernel 1: prep = pack_w fp4 (blocks 0..287) + bin_bits (blocks 288..1855).
// pack_w: thread = one u32 (8 ic nibbles) of Wm. 8 codebook gathers (L2-hot).
// ---------------------------------------------------------------------------
__global__ __launch_bounds__(256) void prep(const int* __restrict__ enc,
                                            const float* __restrict__ cb,
                                            u32* __restrict__ wm,
                                            const float* __restrict__ x,
                                            u64* __restrict__ bp) {
    int bid = blockIdx.x;
    if (bid < 288) {
        int idx = bid * 256 + threadIdx.x;           // 0..73727 u32 words
        int g   = idx & 7;                           // 8B group within 32B row
        int oc  = (idx >> 3) & 255;
        int stp = idx >> 11;                         // 0..35 = tap*4 + k64
        int tap = stp >> 2;
        int k64 = stp & 3;
        u32 word = 0;
#pragma unroll
        for (int e = 0; e < 8; ++e) {
            int i = k64 * 64 + g * 8 + e;            // ic
            int f = oc * 2304 + i * 9 + tap;         // OIHW flat index
            int j = f / 12;
            int t = f - j * 12;
            float v = cb[enc[j] * 12 + t];
            word |= (v < 0.f ? 0xAu : 0x2u) << (4 * e);
        }
        wm[idx] = word;
    } else {
        int gw   = (bid - 288) * 4 + (threadIdx.x >> 6);   // 0..6271
        int lane = threadIdx.x & 63;
        const float* xb = x + (size_t)gw * 4096 + lane;
#pragma unroll 1
        for (int k = 0; k < 8; ++k) {
            float v[8];
#pragma unroll
            for (int j = 0; j < 8; ++j) v[j] = xb[k * 512 + j * 64];
            u64 mine = 0;
#pragma unroll
            for (int j = 0; j < 8; ++j) {
                u64 m = __ballot(v[j] < 0.f);
                if (lane == j) mine = m;
            }
            if (lane < 8) bp[(size_t)gw * 64 + k * 8 + lane] = mine;
        }
    }
}

// ---------------------------------------------------------------------------
// Expand one padded row of bitplanes -> fp4 nibbles in swizzled LDS.
// thread (oct, wseg): channels oct*8..+8 (8 nibbles = u32), w' = wseg+4k.
// Halo -> 0x0 nibbles (+0.0 contributes 0).
// Write addr: wq*256 + ((oct*4) ^ ((wq&15)<<4)) — bijective within the row
// (key bits 4-7, data bits 0-6, XOR cancels on read); write banks
// oct ^ (key>>2): all 32 distinct -> conflict-free.
// ---------------------------------------------------------------------------
__device__ __forceinline__ void expand_row(const u64* __restrict__ bp, u8* xr,
                                           int n, int h, int oct, int wseg) {
    bool rowv = (h >= 0) && (h <= 55);
    int w0c = rowv ? ((h * 56) >> 6) : 0;
    int w1c = w0c + 1; if (w1c > 48) w1c = 48;
    const u64* bq = bp + ((size_t)n * 256 + oct * 8) * 49;
    u64 A[8], B[8];
#pragma unroll
    for (int j = 0; j < 8; ++j) A[j] = bq[j * 49 + w0c];
#pragma unroll
    for (int j = 0; j < 8; ++j) B[j] = bq[j * 49 + w1c];
#pragma unroll 1
    for (int k = 0; k < 15; ++k) {
        int wq = wseg + k * 4;
        if (wq >= 58) break;
        u32 out = 0;
        if (rowv && wq >= 1 && wq <= 56) {
            int px  = h * 56 + wq - 1;
            int bit = px & 63;
            bool s2 = (px >> 6) != w0c;
#pragma unroll
            for (int j = 0; j < 8; ++j) {
                u64 wv = s2 ? B[j] : A[j];
                out |= (((wv >> bit) & 1ull) ? 0xAu : 0x2u) << (4 * j);
            }
        }
        *(u32*)(xr + wq * 256 + ((oct * 4) ^ ((wq & 15) << 4))) = out;
    }
}

// ---------------------------------------------------------------------------
// Kernel 2: MX-FP4 MFMA conv (R14 = R13 + full-width swizzle, single var).
// R13 post-mortem: conv dropped below the top-5 cutoff (<68us) -> fp4 win
// confirmed; last known structural defect = 4-way B-read bank conflict from
// the 128B-row-truncated swizzle key (R12 measured 4.1M of exactly this).
// R14: pad LDS rows to 256B, key (w'&15)<<4 -> 2-way (free, m136). LDS
// 31->60.5KB is FREE: blocks/CU already reg-capped at 2 (acc 64 + ops ~120).
// Everything else byte-identical to R13.
// C/D: col=l&31 (px), row=(q&3)+8*(q>>2)+4*(l>>5) (oc)  [HW-verified].
// ---------------------------------------------------------------------------
__global__ __launch_bounds__(512, 4) void conv_mfma(const u64* __restrict__ bp,
                                                    const char* __restrict__ wm,
                                                    float* __restrict__ y) {
    __shared__ __align__(16) u8 xl[61952];   // 4*14848 + dead-read slack
    int t = threadIdx.x;
    // XCD-aware bijective remap (896 % 8 == 0): 4 consecutive n per XCD.
    int lin = blockIdx.x + 28 * blockIdx.y;
    int swb = (lin & 7) * 112 + (lin >> 3);
    int n   = swb / 28;
    int h0  = (swb - n * 28) * 2;

    int oct = t & 31, wseg = (t >> 5) & 3, rr = t >> 7;
    int wave = t >> 6, lane = t & 63;
    int ocg  = wave & 3;
    int pxg  = wave >> 2;
    int col  = lane & 31;
    int half = lane >> 5;
    int ocw  = ocg * 64;
    int aoff = (ocw + col) * 32 + half * 16;
    int h16  = half * 16;

    // Prime A even-slot with step 0 (global, no LDS dep -> hides under the
    // expansion + barrier).
    const char* wb = wm;
    i32x4 Aea = *(const i32x4*)(wb + aoff);
    i32x4 Aeb = *(const i32x4*)(wb + aoff + 1024);
    wb += 8192;                               // -> step 1

    expand_row(bp, xl + rr * ROWB, n, h0 + rr - 1, oct, wseg);
    __syncthreads();

    int swA = ((col + 0) & 15) << 4, cbA = (col + 0) * 256;
    int swB = ((col + 1) & 15) << 4, cbB = (col + 1) * 256;
    int swC = ((col + 2) & 15) << 4, cbC = (col + 2) * 256;
    int pxb = pxg * ROWB;

    f32x16 acc[2][2] = {};
    i32x4 Aoa, Aob, Be0, Be1, Bo0, Bo1;

#define UP8(V) (i32x8){(V)[0], (V)[1], (V)[2], (V)[3], 0, 0, 0, 0}
#define MFMA4(AA, AB, B0, B1)                                                  \
    acc[0][0] = __builtin_amdgcn_mfma_scale_f32_32x32x64_f8f6f4(               \
        UP8(AA), UP8(B0), acc[0][0], 4, 4, 0, 0x7F7F7F7F, 0, 0x7F7F7F7F);      \
    acc[0][1] = __builtin_amdgcn_mfma_scale_f32_32x32x64_f8f6f4(               \
        UP8(AA), UP8(B1), acc[0][1], 4, 4, 0, 0x7F7F7F7F, 0, 0x7F7F7F7F);      \
    acc[1][0] = __builtin_amdgcn_mfma_scale_f32_32x32x64_f8f6f4(               \
        UP8(AB), UP8(B0), acc[1][0], 4, 4, 0, 0x7F7F7F7F, 0, 0x7F7F7F7F);      \
    acc[1][1] = __builtin_amdgcn_mfma_scale_f32_32x32x64_f8f6f4(               \
        UP8(AB), UP8(B1), acc[1][1], 4, 4, 0, 0x7F7F7F7F, 0, 0x7F7F7F7F);

// One region = one tap: 4 K64-steps (kb = 0,32,64,96 data bytes) as 2
// unroll-1 iterations of 2 steps. Second px tile = w'+32 -> +8192B, same key
// ((w'+32)&15 == w'&15). kc2=1's even prefetch (kb=128) stays inside the
// same 256B row (key bits <8): in-bounds, dead.
#define REGION(CBASE, SWV)                                                     \
    {                                                                          \
        const int _bb = (CBASE);                                               \
        {                                                                      \
            int _p = _bb + (h16 ^ (SWV));                                      \
            Be0 = *(const i32x4*)&xl[_p];                                      \
            Be1 = *(const i32x4*)&xl[_p + 8192];                               \
        }                                                                      \
        _Pragma("unroll 1")                                                    \
        for (int kc2 = 0; kc2 < 2; ++kc2) {                                    \
            int _kb = kc2 * 64;                                                \
            int _ko = _bb + (((_kb + 32) + h16) ^ (SWV));                      \
            Bo0 = *(const i32x4*)&xl[_ko];                                     \
            Bo1 = *(const i32x4*)&xl[_ko + 8192];                              \
            Aoa = *(const i32x4*)(wb + aoff);                                  \
            Aob = *(const i32x4*)(wb + aoff + 1024);                           \
            wb += 8192;                                                        \
            MFMA4(Aea, Aeb, Be0, Be1)                                          \
            int _ke = _bb + (((_kb + 64) + h16) ^ (SWV));                      \
            Be0 = *(const i32x4*)&xl[_ke];                                     \
            Be1 = *(const i32x4*)&xl[_ke + 8192];                              \
            Aea = *(const i32x4*)(wb + aoff);                                  \
            Aeb = *(const i32x4*)(wb + aoff + 1024);                           \
            wb += 8192;                                                        \
            MFMA4(Aoa, Aob, Bo0, Bo1)                                          \
        }                                                                      \
    }

#pragma unroll 1
    for (int r = 0; r < 3; ++r) {
        int rowb = pxb + r * ROWB;
        REGION(rowb + cbA, swA)
        REGION(rowb + cbB, swB)
        REGION(rowb + cbC, swC)
    }
#undef REGION
#undef MFMA4
#undef UP8

    // Final Ae prefetch walked to step 37 (within ws gap below bp): dead, ok.
    int h = h0 + pxg;
    float* yb = y + (size_t)n * 256 * 3136 + (size_t)h * 56;
#pragma unroll
    for (int at = 0; at < 2; ++at) {
#pragma unroll
        for (int bt = 0; bt < 2; ++bt) {
            int w = bt * 32 + col;
            if (w < 56) {
#pragma unroll
                for (int q = 0; q < 16; ++q) {
                    int oc = ocw + at * 32 + (q & 3) + 8 * (q >> 2) + 4 * half;
                    yb[(size_t)oc * 3136 + w] = acc[at][bt][q];
                }
            }
        }
    }
}

extern "C" void kernel_launch(void* const* d_in, const int* in_sizes, int n_in,
                              void* d_out, int out_size, void* d_ws, size_t ws_size,
                              hipStream_t stream) {
    const float* x  = (const float*)d_in[0];
    // d_in[1] (latent weight) unused in the STE forward value.
    const float* cb = (const float*)d_in[2];
    const int* enc  = (const int*)d_in[3];
    float* y        = (float*)d_out;

    u32*  wmc = (u32*)((char*)d_ws + WM_OFF);
    u64*  bp  = (u64*)((char*)d_ws + BP_OFF);

    hipLaunchKernelGGL(prep, dim3(1856), dim3(256), 0, stream, enc, cb, wmc, x, bp);
    hipLaunchKernelGGL(conv_mfma, dim3(28, 32), dim3(512), 0, stream, bp,
                       (const char*)wmc, y);
}

// Round 15
// 226.845 us; speedup vs baseline: 1.0683x; 1.0683x over previous
//
#include <hip/hip_runtime.h>

typedef unsigned int u32;
typedef unsigned char u8;
typedef unsigned long long u64;
typedef int i32x4 __attribute__((ext_vector_type(4)));
typedef int i32x8 __attribute__((ext_vector_type(8)));
typedef float f32x16 __attribute__((ext_vector_type(16)));

// Workspace layout (3.8 MB used):
//   [0, 294912)          Wm fp4: [stp=tap*4+k64][oc][32B] (64 ic nibbles/oc),
//                        8KB per step; nibble 0x2=+1, 0xA=-1 (e2m1).
//   [589824, +3211264)   bp bitplanes: bp[(n*256+ch)*49 + (px>>6)], bit px&63
#define WM_OFF 0
#define BP_OFF 589824
#define ROWB 7424   // LDS bytes per padded row: 58 w' * 128B (256 ic nibbles)

// ---------------------------------------------------------------------------
// Kernel 1: prep = pack_w fp4 (blocks 0..287) + bin_bits (blocks 288..1855).
// ---------------------------------------------------------------------------
__global__ __launch_bounds__(256) void prep(const int* __restrict__ enc,
                                            const float* __restrict__ cb,
                                            u32* __restrict__ wm,
                                            const float* __restrict__ x,
                                            u64* __restrict__ bp) {
    int bid = blockIdx.x;
    if (bid < 288) {
        int idx = bid * 256 + threadIdx.x;           // 0..73727 u32 words
        int g   = idx & 7;                           // 8B group within 32B row
        int oc  = (idx >> 3) & 255;
        int stp = idx >> 11;                         // 0..35 = tap*4 + k64
        int tap = stp >> 2;
        int k64 = stp & 3;
        u32 word = 0;
#pragma unroll
        for (int e = 0; e < 8; ++e) {
            int i = k64 * 64 + g * 8 + e;            // ic
            int f = oc * 2304 + i * 9 + tap;         // OIHW flat index
            int j = f / 12;
            int t = f - j * 12;
            float v = cb[enc[j] * 12 + t];
            word |= (v < 0.f ? 0xAu : 0x2u) << (4 * e);
        }
        wm[idx] = word;
    } else {
        int gw   = (bid - 288) * 4 + (threadIdx.x >> 6);   // 0..6271
        int lane = threadIdx.x & 63;
        const float* xb = x + (size_t)gw * 4096 + lane;
#pragma unroll 1
        for (int k = 0; k < 8; ++k) {
            float v[8];
#pragma unroll
            for (int j = 0; j < 8; ++j) v[j] = xb[k * 512 + j * 64];
            u64 mine = 0;
#pragma unroll
            for (int j = 0; j < 8; ++j) {
                u64 m = __ballot(v[j] < 0.f);
                if (lane == j) mine = m;
            }
            if (lane < 8) bp[(size_t)gw * 64 + k * 8 + lane] = mine;
        }
    }
}

// ---------------------------------------------------------------------------
// Expand one padded row of bitplanes -> fp4 nibbles in swizzled LDS (128B
// rows, R13 layout). thread (oct, wseg): channels oct*8..+8, w' = wseg+4k.
// Halo -> 0x0 nibbles. Write: wq*128 + ((oct*4) ^ ((wq&7)<<4)).
// ---------------------------------------------------------------------------
__device__ __forceinline__ void expand_row(const u64* __restrict__ bp, u8* xr,
                                           int n, int h, int oct, int wseg) {
    bool rowv = (h >= 0) && (h <= 55);
    int w0c = rowv ? ((h * 56) >> 6) : 0;
    int w1c = w0c + 1; if (w1c > 48) w1c = 48;
    const u64* bq = bp + ((size_t)n * 256 + oct * 8) * 49;
    u64 A[8], B[8];
#pragma unroll
    for (int j = 0; j < 8; ++j) A[j] = bq[j * 49 + w0c];
#pragma unroll
    for (int j = 0; j < 8; ++j) B[j] = bq[j * 49 + w1c];
#pragma unroll 1
    for (int k = 0; k < 15; ++k) {
        int wq = wseg + k * 4;
        if (wq >= 58) break;
        u32 out = 0;
        if (rowv && wq >= 1 && wq <= 56) {
            int px  = h * 56 + wq - 1;
            int bit = px & 63;
            bool s2 = (px >> 6) != w0c;
#pragma unroll
            for (int j = 0; j < 8; ++j) {
                u64 wv = s2 ? B[j] : A[j];
                out |= (((wv >> bit) & 1ull) ? 0xAu : 0x2u) << (4 * j);
            }
        }
        *(u32*)(xr + wq * 128 + ((oct * 4) ^ ((wq & 7) << 4))) = out;
    }
}

// ---------------------------------------------------------------------------
// Kernel 2: MX-FP4 MFMA conv (R15 = occupancy-tier jump).
// R14 post-mortem: swizzle null -> conflicts not critical; conv stuck at
// ~60us because 120 total regs lock the <=128 tier (16 waves/CU; m69 tiers
// step only at 64/128/256). R15 halves the wave tile: 8 waves x (32 oc x
// 64 px), 1 output row/block, acc = 2x16 f32 = 32 regs -> TOTAL <= 64 regs
// (launch_bounds(512,8)) -> 32 waves/CU. K-loop goes SIMPLE (unroll 1, no
// slots): per step {2 ds_read, 1 A-load, 2 MFMA}; 8 waves/SIMD cover the
// ~150cyc chain (8 x 36cyc MFMA issue = 288 > 150). LDS = R13 128B-row
// layout, 22.3KB -> 4 blocks/CU (90KB < 160KB).
// Tells: VGPR>64 = cap miss (parity, revert); WRITE>120MB = spill (revert).
// C/D: col=l&31 (px), row=(q&3)+8*(q>>2)+4*(l>>5) (oc)  [HW-verified].
// ---------------------------------------------------------------------------
__global__ __launch_bounds__(512, 8) void conv_mfma(const u64* __restrict__ bp,
                                                    const char* __restrict__ wm,
                                                    float* __restrict__ y) {
    __shared__ __align__(16) u8 xl[23552];   // 3*7424=22272 + over-read slack
    int t = threadIdx.x;
    // XCD-aware bijective remap (1792 % 8 == 0): 224 consecutive tiles/XCD.
    int lin = blockIdx.x + 56 * blockIdx.y;
    int swb = (lin & 7) * 224 + (lin >> 3);
    int n   = swb / 56;
    int h   = swb - n * 56;                  // output row 0..55

    int oct = t & 31, wseg = (t >> 5) & 3, rr = t >> 7;
    int wave = t >> 6, lane = t & 63;
    int col  = lane & 31;
    int half = lane >> 5;
    int ocb  = wave * 32;                    // 8 waves x 32 oc = 256
    int aoff = (ocb + col) * 32 + half * 16;
    int h16  = half * 16;

    if (rr < 3)
        expand_row(bp, xl + rr * ROWB, n, h + rr - 1, oct, wseg);
    __syncthreads();

    int swA = ((col + 0) & 7) << 4, cbA = (col + 0) * 128;
    int swB = ((col + 1) & 7) << 4, cbB = (col + 1) * 128;
    int swC = ((col + 2) & 7) << 4, cbC = (col + 2) * 128;

    f32x16 acc[2] = {};
    const char* wb = wm;

#define UP8(V) (i32x8){(V)[0], (V)[1], (V)[2], (V)[3], 0, 0, 0, 0}
// One region = one tap: 4 K64-steps, unroll 1 (hoist-proof; TLP hides the
// per-step chain at 8 waves/SIMD). Second px tile = +4096B, same key.
#define REGION(CBASE, SWV)                                                     \
    _Pragma("unroll 1")                                                        \
    for (int kc = 0; kc < 4; ++kc) {                                           \
        int _ba = (CBASE) + (((kc * 32) + h16) ^ (SWV));                       \
        i32x4 b0 = *(const i32x4*)&xl[_ba];                                    \
        i32x4 b1 = *(const i32x4*)&xl[_ba + 4096];                             \
        i32x4 a  = *(const i32x4*)(wb + aoff);                                 \
        wb += 8192;                                                            \
        acc[0] = __builtin_amdgcn_mfma_scale_f32_32x32x64_f8f6f4(              \
            UP8(a), UP8(b0), acc[0], 4, 4, 0, 0x7F7F7F7F, 0, 0x7F7F7F7F);      \
        acc[1] = __builtin_amdgcn_mfma_scale_f32_32x32x64_f8f6f4(              \
            UP8(a), UP8(b1), acc[1], 4, 4, 0, 0x7F7F7F7F, 0, 0x7F7F7F7F);      \
    }

#pragma unroll 1
    for (int r = 0; r < 3; ++r) {
        int rowb = r * ROWB;
        REGION(rowb + cbA, swA)
        REGION(rowb + cbB, swB)
        REGION(rowb + cbC, swC)
    }
#undef REGION
#undef UP8

    float* yb = y + (size_t)n * 256 * 3136 + (size_t)h * 56;
#pragma unroll
    for (int bt = 0; bt < 2; ++bt) {
        int w = bt * 32 + col;
        if (w < 56) {
#pragma unroll
            for (int q = 0; q < 16; ++q) {
                int oc = ocb + (q & 3) + 8 * (q >> 2) + 4 * half;
                yb[(size_t)oc * 3136 + w] = acc[bt][q];
            }
        }
    }
}

extern "C" void kernel_launch(void* const* d_in, const int* in_sizes, int n_in,
                              void* d_out, int out_size, void* d_ws, size_t ws_size,
                              hipStream_t stream) {
    const float* x  = (const float*)d_in[0];
    // d_in[1] (latent weight) unused in the STE forward value.
    const float* cb = (const float*)d_in[2];
    const int* enc  = (const int*)d_in[3];
    float* y        = (float*)d_out;

    u32*  wmc = (u32*)((char*)d_ws + WM_OFF);
    u64*  bp  = (u64*)((char*)d_ws + BP_OFF);

    hipLaunchKernelGGL(prep, dim3(1856), dim3(256), 0, stream, enc, cb, wmc, x, bp);
    hipLaunchKernelGGL(conv_mfma, dim3(56, 32), dim3(512), 0, stream, bp,
                       (const char*)wmc, y);
}